// Round 11
// baseline (3236.749 us; speedup 1.0000x reference)
//
#include <hip/hip_runtime.h>
#include <math.h>

// Semi-relaxed Sinkhorn-Knopp, MI355X. B=16, n=4096, k=1024, K=1025.
// R11 = R10 + ONE lever: 2-row Q prefetch issued BEFORE the fin-at-head
// phase (16 VGPRs; 36+16=52 <= 64 budget at __launch_bounds__(512,4) — the
// contained version of R8's over-dosed idea). Loads drain during fin's L2
// reads + exp2/log2; consumed right after the barrier; rows 2..15 loop.
// Everything else identical to R10:
//  - 1 launch/iter, zero sync/atomics, redundant fin-at-head, part ping-pong
//  - MODE3 plan from stored bf16 Q in d_ws (no logits re-read, no exp2)
//  - MODE0 prep: direct lse, no max pass (N(0,1) fp32-safe)

namespace {
constexpr int   Bn      = 16;
constexpr int   Kc      = 1024;    // k
constexpr int   KK      = 1025;    // K = k+1 (dustbin)
constexpr int   BSTR    = 1028;    // padded b stride
constexpr int   ROWS    = 65536;   // B*n
constexpr int   NBLK    = 512;     // blocks; 32 per batch
constexpr int   TPB     = 512;     // threads; 8 waves
constexpr int   SUBS    = 32;      // blocks per batch
constexpr int   RPB     = 128;     // rows per block
constexpr float PA      = 1.0f / 4096.0f;
constexpr float PB_LOW  = (float)(0.5 / 1024.0);
constexpr float PB_DUST = 0.5f;
constexpr float FI_F    = (float)(1.0 / 1.1); // GAMMA/(GAMMA+EPS)
constexpr float STOP    = 1e-6f;
constexpr int   NITER   = 100;
constexpr float LOG2E   = 1.44269504088896340736f;
constexpr float ILOG2E  = 0.69314718055994530942f;  // ln2
constexpr float TLOG2E  = 14.4269504088896340736f;  // 10*log2(e)
constexpr float B0      = (float)(1.0 / 1025.0);
constexpr size_t QBYTES = (size_t)ROWS * 1024 * 2;          // 128 MiB
constexpr size_t FWORDS = (size_t)Bn * BSTR + 2 * ROWS +
                          2 * (size_t)Bn * SUBS * Kc + 2 * NBLK + NITER * Bn;
} // namespace

typedef __attribute__((ext_vector_type(8))) unsigned short ushort8;

__device__ __forceinline__ float wredsum(float v) {
#pragma unroll
  for (int m = 32; m >= 1; m >>= 1) v += __shfl_xor(v, m, 64);
  return v;
}
__device__ __forceinline__ unsigned short f2bf(float x) {
  unsigned int u = __float_as_uint(x);
  return (unsigned short)((u + 0x7FFFu + ((u >> 16) & 1u)) >> 16);  // RNE
}
__device__ __forceinline__ float bf2f(unsigned short h) {
  return __uint_as_float(((unsigned int)h) << 16);
}

// one row of the fused iteration: dot(Q_row,b) -> a ; acc += Q_row * a
__device__ __forceinline__ void consume_row(
    const ushort8 qa, const ushort8 qb2, const float4* bb, const float bdust,
    float* acc, float& sal, float* __restrict__ avec, const int row,
    const int lane) {
  float q[16];
#pragma unroll
  for (int e = 0; e < 8; ++e) { q[e] = bf2f(qa[e]); q[8 + e] = bf2f(qb2[e]); }
  float p = 0.0f;
#pragma unroll
  for (int s = 0; s < 4; ++s)
    p += q[s * 4 + 0] * bb[s].x + q[s * 4 + 1] * bb[s].y +
         q[s * 4 + 2] * bb[s].z + q[s * 4 + 3] * bb[s].w;
  const float inner = wredsum(p) + bdust;        // dustbin Q == 1
  const float a = PA / inner;                    // broadcast to all lanes
  if (lane == 0) { avec[row] = a; sal += a; }
#pragma unroll
  for (int e = 0; e < 16; ++e) acc[e] += q[e] * a;
}

// ---------------- init ----------------
__global__ void k_init(float* __restrict__ bstore, float* __restrict__ e2vec) {
  int tid = blockIdx.x * blockDim.x + threadIdx.x;
  int stride = gridDim.x * blockDim.x;
  for (int i = tid; i < Bn * BSTR; i += stride) {
    int j = i % BSTR;
    bstore[i] = (j < KK) ? B0 : 0.0f;
  }
  for (int i = tid; i < NITER * Bn; i += stride)
    e2vec[i] = (i == 0) ? 1.0f : 0.0f;   // err_0 = 1.0, like the reference
}

// MODE: 0 first iter (prep fused, b const) | 1 mid iter |
//       2 plan-from-logits (fallback)      | 3 plan-from-Qb (ws path)
template <int MODE>
__global__ __launch_bounds__(512, 4) void k_step(
    const float* __restrict__ x, unsigned short* __restrict__ Qb,
    float* __restrict__ lsev, float* __restrict__ avec,
    float* __restrict__ bstore,
    const float* __restrict__ partIn, float* __restrict__ partOut,
    const float* __restrict__ sumaIn, float* __restrict__ sumaOut,
    float* __restrict__ e2vec, float* __restrict__ out, const int t) {
  __shared__ float bls[1026];
  __shared__ float cpart[8][1024];
  __shared__ float sred[8];
  __shared__ int sstop_s;
  const int tid = threadIdx.x, wave = tid >> 6, lane = tid & 63;
  const int blk = blockIdx.x, b = blk >> 5, sub = blk & 31;
  const int j2 = tid << 1;
  const int rowBase = blk * RPB + wave * 16;
  const ushort8* qrow = (const ushort8*)Qb + ((size_t)rowBase << 7) + (lane << 1);

  // --- 2-row prefetch: 16 VGPRs, issued before fin; drain during fin ---
  ushort8 pfa0, pfb0, pfa1, pfb1;
  if constexpr (MODE == 1) {
    pfa0 = qrow[0];   pfb0 = qrow[1];
    pfa1 = qrow[128]; pfb1 = qrow[129];
  }

  float bn0 = 0.0f, bn1 = 0.0f;
  if constexpr (MODE != 0) {
    if (wave == 0) {          // stop gate from iteration t-1 (wave-parallel)
      float g = (lane < Bn) ? e2vec[(t - 1) * Bn + lane] : 0.0f;
      g = wredsum(g);
      if (lane == 0) sstop_s = (!(sqrtf(g) > STOP)) ? 1 : 0;  // NaN stops too
    }
    {                          // redundant fin: this batch's 32x1024 partials
      const float* pb = partIn + ((size_t)b << 15);
      float s0 = 0.0f, s1 = 0.0f;
#pragma unroll 8
      for (int sb = 0; sb < SUBS; ++sb) {
        const float2 v = *(const float2*)(pb + (sb << 10) + j2);
        s0 += v.x; s1 += v.y;
      }
      bn0 = exp2f(FI_F * log2f(PB_LOW / s0));
      bn1 = exp2f(FI_F * log2f(PB_LOW / s1));
      bls[j2] = bn0; bls[j2 + 1] = bn1;
    }
    if (wave == 1) {           // dustbin
      float sa = (lane < SUBS) ? sumaIn[(b << 5) + lane] : 0.0f;
      sa = wredsum(sa);
      if (lane == 0) bls[1024] = PB_DUST / sa;
    }
    __syncthreads();
    const int sstop = sstop_s;
    if constexpr (MODE == 1) {
      if (sstop) return;
      if (sub == 0) {          // e2 + bstore commit (one block per batch)
        const float bo0 = bstore[b * BSTR + j2];
        const float bo1 = bstore[b * BSTR + j2 + 1];
        float e2 = (bn0 - bo0) * (bn0 - bo0) + (bn1 - bo1) * (bn1 - bo1);
        const float ew = wredsum(e2);
        if (lane == 0) sred[wave] = ew;
        __syncthreads();
        if (tid == 0) {
          float tt = 0.0f;
#pragma unroll
          for (int w = 0; w < 8; ++w) tt += sred[w];
          const float bd = bls[1024], bod = bstore[b * BSTR + 1024];
          tt += (bd - bod) * (bd - bod);
          e2vec[t * Bn + b] = tt;
          bstore[b * BSTR + 1024] = bd;
        }
        __syncthreads();       // protect sred reuse by the Q-pass tail
        bstore[b * BSTR + j2]     = bn0;
        bstore[b * BSTR + j2 + 1] = bn1;
      }
    } else {
      if (sstop) {             // stopped earlier: final b is in bstore
        bls[j2]     = bstore[b * BSTR + j2];
        bls[j2 + 1] = bstore[b * BSTR + j2 + 1];
        if (tid == 0) bls[1024] = bstore[b * BSTR + 1024];
      }
      __syncthreads();
    }
  }

  // ---- b into registers ----
  float4 bb[4];
  float bdust;
  if constexpr (MODE == 0) {
    const float4 c = make_float4(B0, B0, B0, B0);
#pragma unroll
    for (int s = 0; s < 4; ++s) bb[s] = c;
    bdust = B0;
  } else {
#pragma unroll
    for (int s = 0; s < 4; ++s) bb[s] = *(const float4*)&bls[(lane << 4) + (s << 2)];
    bdust = bls[1024];
  }

  if constexpr (MODE == 2) {   // fallback plan: recompute Q from logits+lse
#pragma unroll 2
    for (int r = 0; r < 16; ++r) {
      const int row = rowBase + r;
      const float lse = lsev[row];
      const float sc = avec[row] * 4096.0f;
      const float4* xp = (const float4*)(x + ((size_t)row << 10));
      float4* op = (float4*)(out + ((size_t)row << 10));
#pragma unroll
      for (int s = 0; s < 4; ++s) {
        const float4 v = xp[(lane << 2) + s];
        float4 o;
        o.x = exp2f((v.x - lse) * TLOG2E) * sc * bb[s].x;
        o.y = exp2f((v.y - lse) * TLOG2E) * sc * bb[s].y;
        o.z = exp2f((v.z - lse) * TLOG2E) * sc * bb[s].z;
        o.w = exp2f((v.w - lse) * TLOG2E) * sc * bb[s].w;
        op[(lane << 2) + s] = o;
      }
    }
    return;
  }

  if constexpr (MODE == 3) {   // ws-path plan: out = a * Qb * b * n
#pragma unroll 2
    for (int r = 0; r < 16; ++r) {
      const int row = rowBase + r;
      const ushort8 ua = qrow[r << 7], ub = qrow[(r << 7) + 1];
      const float sc = avec[row] * 4096.0f;
      float4* op = (float4*)(out + ((size_t)row << 10));
      float q[16];
#pragma unroll
      for (int e = 0; e < 8; ++e) { q[e] = bf2f(ua[e]); q[8 + e] = bf2f(ub[e]); }
#pragma unroll
      for (int s = 0; s < 4; ++s) {
        float4 o;
        o.x = q[s * 4 + 0] * sc * bb[s].x;
        o.y = q[s * 4 + 1] * sc * bb[s].y;
        o.z = q[s * 4 + 2] * sc * bb[s].z;
        o.w = q[s * 4 + 3] * sc * bb[s].w;
        op[(lane << 2) + s] = o;
      }
    }
    return;
  }

  // ---------------- Q-pass (MODE 0/1) ----------------
  float acc[16];
#pragma unroll
  for (int e = 0; e < 16; ++e) acc[e] = 0.0f;
  float sal = 0.0f;

  if constexpr (MODE == 0) {
    // prep: direct lse (no max pass; logits ~ N(0,1), fp32-safe), Q bf16 out
#pragma unroll 2
    for (int r = 0; r < 16; ++r) {
      const int row = rowBase + r;
      const float4* xp = (const float4*)(x + ((size_t)row << 10));
      float4 v[4];
#pragma unroll
      for (int s = 0; s < 4; ++s) v[s] = xp[(lane << 2) + s];
      float su = 0.0f;
#pragma unroll
      for (int s = 0; s < 4; ++s)
        su += exp2f(v[s].x * LOG2E) + exp2f(v[s].y * LOG2E) +
              exp2f(v[s].z * LOG2E) + exp2f(v[s].w * LOG2E);
      su = wredsum(su);
      const float lse = log2f(su) * ILOG2E;
      if (lane == 0) lsev[row] = lse;
      float q[16];
      ushort8 ua, ub;
#pragma unroll
      for (int s = 0; s < 4; ++s) {
        const unsigned short u0 = f2bf(exp2f((v[s].x - lse) * TLOG2E));
        const unsigned short u1 = f2bf(exp2f((v[s].y - lse) * TLOG2E));
        const unsigned short u2 = f2bf(exp2f((v[s].z - lse) * TLOG2E));
        const unsigned short u3 = f2bf(exp2f((v[s].w - lse) * TLOG2E));
        if (s < 2) { ua[s*4+0]=u0; ua[s*4+1]=u1; ua[s*4+2]=u2; ua[s*4+3]=u3; }
        else { ub[(s-2)*4+0]=u0; ub[(s-2)*4+1]=u1; ub[(s-2)*4+2]=u2; ub[(s-2)*4+3]=u3; }
        q[s*4+0]=bf2f(u0); q[s*4+1]=bf2f(u1); q[s*4+2]=bf2f(u2); q[s*4+3]=bf2f(u3);
      }
      ushort8* qp = (ushort8*)(Qb + ((size_t)row << 10));
      qp[lane * 2] = ua; qp[lane * 2 + 1] = ub;
      float sq = 0.0f;
#pragma unroll
      for (int e = 0; e < 16; ++e) sq += q[e];
      const float inner = (wredsum(sq) + 1.0f) * B0;   // b const, dustbin Q==1
      const float a = PA / inner;
      if (lane == 0) { avec[row] = a; sal += a; }
#pragma unroll
      for (int e = 0; e < 16; ++e) acc[e] += q[e] * a;
    }
  } else {
    // rows 0-1 from prefetch (loads were in flight across the fin barrier)
    consume_row(pfa0, pfb0, bb, bdust, acc, sal, avec, rowBase + 0, lane);
    consume_row(pfa1, pfb1, bb, bdust, acc, sal, avec, rowBase + 1, lane);
    // rows 2..15: R7-style single-row steps
#pragma unroll 2
    for (int r = 2; r < 16; ++r) {
      const ushort8 qa = qrow[r << 7], qb2 = qrow[(r << 7) + 1];
      consume_row(qa, qb2, bb, bdust, acc, sal, avec, rowBase + r, lane);
    }
  }

  if (lane == 0) sred[wave] = sal;
  float4* cp = (float4*)&cpart[wave][lane << 4];
#pragma unroll
  for (int s = 0; s < 4; ++s)
    cp[s] = make_float4(acc[s * 4 + 0], acc[s * 4 + 1], acc[s * 4 + 2], acc[s * 4 + 3]);
  __syncthreads();

  float o0 = 0.0f, o1 = 0.0f;
#pragma unroll
  for (int w = 0; w < 8; ++w) { o0 += cpart[w][j2]; o1 += cpart[w][j2 + 1]; }
  *(float2*)(partOut + ((size_t)b << 15) + (sub << 10) + j2) = make_float2(o0, o1);
  if (tid == 0) {
    float ss = 0.0f;
#pragma unroll
    for (int w = 0; w < 8; ++w) ss += sred[w];
    sumaOut[(b << 5) + sub] = ss;
  }
}

extern "C" void kernel_launch(void* const* d_in, const int* in_sizes, int n_in,
                              void* d_out, int out_size, void* d_ws, size_t ws_size,
                              hipStream_t stream) {
  const float* logits = (const float*)d_in[0];
  const bool wsfit = ws_size >= QBYTES + FWORDS * sizeof(float);

  unsigned short* Qb;
  float* fbase;
  if (wsfit) {            // Q bf16 in workspace; plan reads it directly
    Qb = (unsigned short*)d_ws;
    fbase = (float*)((char*)d_ws + QBYTES);
  } else {                // fallback: Q bf16 in d_out's first half
    Qb = (unsigned short*)d_out;
    fbase = (float*)d_ws;
  }
  float* bstore = fbase;                           // 16*1028
  float* avec   = bstore + Bn * BSTR;              // 65536
  float* lsev   = avec + ROWS;                     // 65536
  float* partA  = lsev + ROWS;                     // 16*32*1024
  float* partB  = partA + (size_t)Bn * SUBS * Kc;  // 16*32*1024
  float* sumaA  = partB + (size_t)Bn * SUBS * Kc;  // 512
  float* sumaB  = sumaA + NBLK;                    // 512
  float* e2vec  = sumaB + NBLK;                    // 100*16

  k_init<<<16, 256, 0, stream>>>(bstore, e2vec);
  k_step<0><<<NBLK, TPB, 0, stream>>>(logits, Qb, lsev, avec, bstore,
                                      partA, partA, sumaA, sumaA, e2vec,
                                      nullptr, 0);
  for (int t = 1; t < NITER; ++t) {
    const bool odd = (t & 1) != 0;
    k_step<1><<<NBLK, TPB, 0, stream>>>(logits, Qb, lsev, avec, bstore,
                                        odd ? partA : partB, odd ? partB : partA,
                                        odd ? sumaA : sumaB, odd ? sumaB : sumaA,
                                        e2vec, nullptr, t);
  }
  // t = 99 (odd) wrote partB/sumaB
  if (wsfit)
    k_step<3><<<NBLK, TPB, 0, stream>>>(logits, Qb, lsev, avec, bstore,
                                        partB, partA, sumaB, sumaA, e2vec,
                                        (float*)d_out, NITER);
  else
    k_step<2><<<NBLK, TPB, 0, stream>>>(logits, Qb, lsev, avec, bstore,
                                        partB, partA, sumaB, sumaA, e2vec,
                                        (float*)d_out, NITER);
}

// Round 12
// 3014.111 us; speedup vs baseline: 1.0739x; 1.0739x over previous
//
#include <hip/hip_runtime.h>
#include <math.h>

// Semi-relaxed Sinkhorn-Knopp, MI355X. B=16, n=4096, k=1024, K=1025.
// R12 = R10 verbatim (best measured: 3.018 ms). R11's 2-row prefetch
// regressed (+2us/iter: values held across __syncthreads force a
// vmcnt(0) drain BEFORE the barrier -> serializes instead of overlapping).
// Pipelining ledger closed: R8 (deep prefetch, spills), R9 (two-row
// interleave), R11 (light prefetch) ALL lose to this plain unroll-4 loop.
// Structure: 1 launch/iter, zero sync/atomics, redundant fin-at-head,
// part ping-pong, lag-1 stop gate; MODE3 plan from stored bf16 Q in d_ws;
// MODE0 prep with direct lse (no max pass; N(0,1) logits are fp32-safe).

namespace {
constexpr int   Bn      = 16;
constexpr int   Kc      = 1024;    // k
constexpr int   KK      = 1025;    // K = k+1 (dustbin)
constexpr int   BSTR    = 1028;    // padded b stride
constexpr int   ROWS    = 65536;   // B*n
constexpr int   NBLK    = 512;     // blocks; 32 per batch
constexpr int   TPB     = 512;     // threads; 8 waves
constexpr int   SUBS    = 32;      // blocks per batch
constexpr int   RPB     = 128;     // rows per block
constexpr float PA      = 1.0f / 4096.0f;
constexpr float PB_LOW  = (float)(0.5 / 1024.0);
constexpr float PB_DUST = 0.5f;
constexpr float FI_F    = (float)(1.0 / 1.1); // GAMMA/(GAMMA+EPS)
constexpr float STOP    = 1e-6f;
constexpr int   NITER   = 100;
constexpr float LOG2E   = 1.44269504088896340736f;
constexpr float ILOG2E  = 0.69314718055994530942f;  // ln2
constexpr float TLOG2E  = 14.4269504088896340736f;  // 10*log2(e)
constexpr float B0      = (float)(1.0 / 1025.0);
constexpr size_t QBYTES = (size_t)ROWS * 1024 * 2;          // 128 MiB
constexpr size_t FWORDS = (size_t)Bn * BSTR + 2 * ROWS +
                          2 * (size_t)Bn * SUBS * Kc + 2 * NBLK + NITER * Bn;
} // namespace

typedef __attribute__((ext_vector_type(8))) unsigned short ushort8;

__device__ __forceinline__ float wredsum(float v) {
#pragma unroll
  for (int m = 32; m >= 1; m >>= 1) v += __shfl_xor(v, m, 64);
  return v;
}
__device__ __forceinline__ unsigned short f2bf(float x) {
  unsigned int u = __float_as_uint(x);
  return (unsigned short)((u + 0x7FFFu + ((u >> 16) & 1u)) >> 16);  // RNE
}
__device__ __forceinline__ float bf2f(unsigned short h) {
  return __uint_as_float(((unsigned int)h) << 16);
}

// ---------------- init ----------------
__global__ void k_init(float* __restrict__ bstore, float* __restrict__ e2vec) {
  int tid = blockIdx.x * blockDim.x + threadIdx.x;
  int stride = gridDim.x * blockDim.x;
  for (int i = tid; i < Bn * BSTR; i += stride) {
    int j = i % BSTR;
    bstore[i] = (j < KK) ? B0 : 0.0f;
  }
  for (int i = tid; i < NITER * Bn; i += stride)
    e2vec[i] = (i == 0) ? 1.0f : 0.0f;   // err_0 = 1.0, like the reference
}

// MODE: 0 first iter (prep fused, b const) | 1 mid iter |
//       2 plan-from-logits (fallback)      | 3 plan-from-Qb (ws path)
template <int MODE>
__global__ __launch_bounds__(512, 4) void k_step(
    const float* __restrict__ x, unsigned short* __restrict__ Qb,
    float* __restrict__ lsev, float* __restrict__ avec,
    float* __restrict__ bstore,
    const float* __restrict__ partIn, float* __restrict__ partOut,
    const float* __restrict__ sumaIn, float* __restrict__ sumaOut,
    float* __restrict__ e2vec, float* __restrict__ out, const int t) {
  __shared__ float bls[1026];
  __shared__ float cpart[8][1024];
  __shared__ float sred[8];
  __shared__ int sstop_s;
  const int tid = threadIdx.x, wave = tid >> 6, lane = tid & 63;
  const int blk = blockIdx.x, b = blk >> 5, sub = blk & 31;
  const int j2 = tid << 1;
  const int rowBase = blk * RPB + wave * 16;
  const ushort8* qrow = (const ushort8*)Qb + ((size_t)rowBase << 7) + (lane << 1);

  float bn0 = 0.0f, bn1 = 0.0f;
  if constexpr (MODE != 0) {
    if (wave == 0) {          // stop gate from iteration t-1 (wave-parallel)
      float g = (lane < Bn) ? e2vec[(t - 1) * Bn + lane] : 0.0f;
      g = wredsum(g);
      if (lane == 0) sstop_s = (!(sqrtf(g) > STOP)) ? 1 : 0;  // NaN stops too
    }
    {                          // redundant fin: this batch's 32x1024 partials
      const float* pb = partIn + ((size_t)b << 15);
      float s0 = 0.0f, s1 = 0.0f;
#pragma unroll 8
      for (int sb = 0; sb < SUBS; ++sb) {
        const float2 v = *(const float2*)(pb + (sb << 10) + j2);
        s0 += v.x; s1 += v.y;
      }
      bn0 = exp2f(FI_F * log2f(PB_LOW / s0));
      bn1 = exp2f(FI_F * log2f(PB_LOW / s1));
      bls[j2] = bn0; bls[j2 + 1] = bn1;
    }
    if (wave == 1) {           // dustbin
      float sa = (lane < SUBS) ? sumaIn[(b << 5) + lane] : 0.0f;
      sa = wredsum(sa);
      if (lane == 0) bls[1024] = PB_DUST / sa;
    }
    __syncthreads();
    const int sstop = sstop_s;
    if constexpr (MODE == 1) {
      if (sstop) return;
      if (sub == 0) {          // e2 + bstore commit (one block per batch)
        const float bo0 = bstore[b * BSTR + j2];
        const float bo1 = bstore[b * BSTR + j2 + 1];
        float e2 = (bn0 - bo0) * (bn0 - bo0) + (bn1 - bo1) * (bn1 - bo1);
        const float ew = wredsum(e2);
        if (lane == 0) sred[wave] = ew;
        __syncthreads();
        if (tid == 0) {
          float tt = 0.0f;
#pragma unroll
          for (int w = 0; w < 8; ++w) tt += sred[w];
          const float bd = bls[1024], bod = bstore[b * BSTR + 1024];
          tt += (bd - bod) * (bd - bod);
          e2vec[t * Bn + b] = tt;
          bstore[b * BSTR + 1024] = bd;
        }
        __syncthreads();       // protect sred reuse by the Q-pass tail
        bstore[b * BSTR + j2]     = bn0;
        bstore[b * BSTR + j2 + 1] = bn1;
      }
    } else {
      if (sstop) {             // stopped earlier: final b is in bstore
        bls[j2]     = bstore[b * BSTR + j2];
        bls[j2 + 1] = bstore[b * BSTR + j2 + 1];
        if (tid == 0) bls[1024] = bstore[b * BSTR + 1024];
      }
      __syncthreads();
    }
  }

  // ---- b into registers ----
  float4 bb[4];
  float bdust;
  if constexpr (MODE == 0) {
    const float4 c = make_float4(B0, B0, B0, B0);
#pragma unroll
    for (int s = 0; s < 4; ++s) bb[s] = c;
    bdust = B0;
  } else {
#pragma unroll
    for (int s = 0; s < 4; ++s) bb[s] = *(const float4*)&bls[(lane << 4) + (s << 2)];
    bdust = bls[1024];
  }

  if constexpr (MODE == 2) {   // fallback plan: recompute Q from logits+lse
#pragma unroll 2
    for (int r = 0; r < 16; ++r) {
      const int row = rowBase + r;
      const float lse = lsev[row];
      const float sc = avec[row] * 4096.0f;
      const float4* xp = (const float4*)(x + ((size_t)row << 10));
      float4* op = (float4*)(out + ((size_t)row << 10));
#pragma unroll
      for (int s = 0; s < 4; ++s) {
        const float4 v = xp[(lane << 2) + s];
        float4 o;
        o.x = exp2f((v.x - lse) * TLOG2E) * sc * bb[s].x;
        o.y = exp2f((v.y - lse) * TLOG2E) * sc * bb[s].y;
        o.z = exp2f((v.z - lse) * TLOG2E) * sc * bb[s].z;
        o.w = exp2f((v.w - lse) * TLOG2E) * sc * bb[s].w;
        op[(lane << 2) + s] = o;
      }
    }
    return;
  }

  if constexpr (MODE == 3) {   // ws-path plan: out = a * Qb * b * n
#pragma unroll 2
    for (int r = 0; r < 16; ++r) {
      const int row = rowBase + r;
      const ushort8 ua = qrow[r << 7], ub = qrow[(r << 7) + 1];
      const float sc = avec[row] * 4096.0f;
      float4* op = (float4*)(out + ((size_t)row << 10));
      float q[16];
#pragma unroll
      for (int e = 0; e < 8; ++e) { q[e] = bf2f(ua[e]); q[8 + e] = bf2f(ub[e]); }
#pragma unroll
      for (int s = 0; s < 4; ++s) {
        float4 o;
        o.x = q[s * 4 + 0] * sc * bb[s].x;
        o.y = q[s * 4 + 1] * sc * bb[s].y;
        o.z = q[s * 4 + 2] * sc * bb[s].z;
        o.w = q[s * 4 + 3] * sc * bb[s].w;
        op[(lane << 2) + s] = o;
      }
    }
    return;
  }

  // ---------------- Q-pass (MODE 0/1) ----------------
  float acc[16];
#pragma unroll
  for (int e = 0; e < 16; ++e) acc[e] = 0.0f;
  float sal = 0.0f;

  if constexpr (MODE == 0) {
    // prep: direct lse (no max pass; logits ~ N(0,1), fp32-safe), Q bf16 out
#pragma unroll 2
    for (int r = 0; r < 16; ++r) {
      const int row = rowBase + r;
      const float4* xp = (const float4*)(x + ((size_t)row << 10));
      float4 v[4];
#pragma unroll
      for (int s = 0; s < 4; ++s) v[s] = xp[(lane << 2) + s];
      float su = 0.0f;
#pragma unroll
      for (int s = 0; s < 4; ++s)
        su += exp2f(v[s].x * LOG2E) + exp2f(v[s].y * LOG2E) +
              exp2f(v[s].z * LOG2E) + exp2f(v[s].w * LOG2E);
      su = wredsum(su);
      const float lse = log2f(su) * ILOG2E;
      if (lane == 0) lsev[row] = lse;
      float q[16];
      ushort8 ua, ub;
#pragma unroll
      for (int s = 0; s < 4; ++s) {
        const unsigned short u0 = f2bf(exp2f((v[s].x - lse) * TLOG2E));
        const unsigned short u1 = f2bf(exp2f((v[s].y - lse) * TLOG2E));
        const unsigned short u2 = f2bf(exp2f((v[s].z - lse) * TLOG2E));
        const unsigned short u3 = f2bf(exp2f((v[s].w - lse) * TLOG2E));
        if (s < 2) { ua[s*4+0]=u0; ua[s*4+1]=u1; ua[s*4+2]=u2; ua[s*4+3]=u3; }
        else { ub[(s-2)*4+0]=u0; ub[(s-2)*4+1]=u1; ub[(s-2)*4+2]=u2; ub[(s-2)*4+3]=u3; }
        q[s*4+0]=bf2f(u0); q[s*4+1]=bf2f(u1); q[s*4+2]=bf2f(u2); q[s*4+3]=bf2f(u3);
      }
      ushort8* qp = (ushort8*)(Qb + ((size_t)row << 10));
      qp[lane * 2] = ua; qp[lane * 2 + 1] = ub;
      float sq = 0.0f;
#pragma unroll
      for (int e = 0; e < 16; ++e) sq += q[e];
      const float inner = (wredsum(sq) + 1.0f) * B0;   // b const, dustbin Q==1
      const float a = PA / inner;
      if (lane == 0) { avec[row] = a; sal += a; }
#pragma unroll
      for (int e = 0; e < 16; ++e) acc[e] += q[e] * a;
    }
  } else {
    // R7's exact hot loop: single row per step, unroll 4
#pragma unroll 4
    for (int r = 0; r < 16; ++r) {
      const ushort8 qa = qrow[r << 7], qb2 = qrow[(r << 7) + 1];
      float q[16];
#pragma unroll
      for (int e = 0; e < 8; ++e) { q[e] = bf2f(qa[e]); q[8 + e] = bf2f(qb2[e]); }

      float p = 0.0f;
#pragma unroll
      for (int s = 0; s < 4; ++s)
        p += q[s * 4 + 0] * bb[s].x + q[s * 4 + 1] * bb[s].y +
             q[s * 4 + 2] * bb[s].z + q[s * 4 + 3] * bb[s].w;

      const float inner = wredsum(p) + bdust;       // dustbin Q == 1
      const float a = PA / inner;                   // broadcast to all lanes
      if (lane == 0) { avec[rowBase + r] = a; sal += a; }
#pragma unroll
      for (int e = 0; e < 16; ++e) acc[e] += q[e] * a;
    }
  }

  if (lane == 0) sred[wave] = sal;
  float4* cp = (float4*)&cpart[wave][lane << 4];
#pragma unroll
  for (int s = 0; s < 4; ++s)
    cp[s] = make_float4(acc[s * 4 + 0], acc[s * 4 + 1], acc[s * 4 + 2], acc[s * 4 + 3]);
  __syncthreads();

  float o0 = 0.0f, o1 = 0.0f;
#pragma unroll
  for (int w = 0; w < 8; ++w) { o0 += cpart[w][j2]; o1 += cpart[w][j2 + 1]; }
  *(float2*)(partOut + ((size_t)b << 15) + (sub << 10) + j2) = make_float2(o0, o1);
  if (tid == 0) {
    float ss = 0.0f;
#pragma unroll
    for (int w = 0; w < 8; ++w) ss += sred[w];
    sumaOut[(b << 5) + sub] = ss;
  }
}

extern "C" void kernel_launch(void* const* d_in, const int* in_sizes, int n_in,
                              void* d_out, int out_size, void* d_ws, size_t ws_size,
                              hipStream_t stream) {
  const float* logits = (const float*)d_in[0];
  const bool wsfit = ws_size >= QBYTES + FWORDS * sizeof(float);

  unsigned short* Qb;
  float* fbase;
  if (wsfit) {            // Q bf16 in workspace; plan reads it directly
    Qb = (unsigned short*)d_ws;
    fbase = (float*)((char*)d_ws + QBYTES);
  } else {                // fallback: Q bf16 in d_out's first half
    Qb = (unsigned short*)d_out;
    fbase = (float*)d_ws;
  }
  float* bstore = fbase;                           // 16*1028
  float* avec   = bstore + Bn * BSTR;              // 65536
  float* lsev   = avec + ROWS;                     // 65536
  float* partA  = lsev + ROWS;                     // 16*32*1024
  float* partB  = partA + (size_t)Bn * SUBS * Kc;  // 16*32*1024
  float* sumaA  = partB + (size_t)Bn * SUBS * Kc;  // 512
  float* sumaB  = sumaA + NBLK;                    // 512
  float* e2vec  = sumaB + NBLK;                    // 100*16

  k_init<<<16, 256, 0, stream>>>(bstore, e2vec);
  k_step<0><<<NBLK, TPB, 0, stream>>>(logits, Qb, lsev, avec, bstore,
                                      partA, partA, sumaA, sumaA, e2vec,
                                      nullptr, 0);
  for (int t = 1; t < NITER; ++t) {
    const bool odd = (t & 1) != 0;
    k_step<1><<<NBLK, TPB, 0, stream>>>(logits, Qb, lsev, avec, bstore,
                                        odd ? partA : partB, odd ? partB : partA,
                                        odd ? sumaA : sumaB, odd ? sumaB : sumaA,
                                        e2vec, nullptr, t);
  }
  // t = 99 (odd) wrote partB/sumaB
  if (wsfit)
    k_step<3><<<NBLK, TPB, 0, stream>>>(logits, Qb, lsev, avec, bstore,
                                        partB, partA, sumaB, sumaA, e2vec,
                                        (float*)d_out, NITER);
  else
    k_step<2><<<NBLK, TPB, 0, stream>>>(logits, Qb, lsev, avec, bstore,
                                        partB, partA, sumaB, sumaA, e2vec,
                                        (float*)d_out, NITER);
}